// Round 6
// baseline (259.430 us; speedup 1.0000x reference)
//
#include <hip/hip_runtime.h>

#define BTOT 4096
#define TS 32

typedef __attribute__((ext_vector_type(8))) short bfrag;   // 8 bf16, 16 B
typedef __attribute__((ext_vector_type(4))) float f32x4;

#define S1 (-1.44269504089f)   // -log2(e)
#define S2 (-2.88539008178f)   // -2*log2(e)

__device__ __forceinline__ short f2bf(float f){
  union { float f; unsigned u; } v; v.f = f;
  unsigned r = v.u + 0x7FFFu + ((v.u >> 16) & 1u);   // RNE
  return (short)(r >> 16);
}
__device__ __forceinline__ float bf2f(short s){
  union { unsigned u; float f; } v; v.u = ((unsigned)(unsigned short)s) << 16; return v.f;
}

struct LstmP {
  const float* x[6];
  const float* wih[6];
  const float* whh[6];
  const float* bias[6];
  float* hout;        // [6][BTOT][64] fp32
};

struct EpiP {
  const float* hout;
  const float* s2;
  const float* w03[2]; const float* b03[2];
  const float* w1[2];  const float* b1[2];
  const float* w2[2];  const float* b2[2];
  float* out;
};

// Block: run = blockIdx.y, 16 batch rows, 2 waves of 64.
// Wave w owns cols j = 32w..32w+31 (2 slices of 16) for ALL 4 gates; lane holds
// i,f,g,o of cells (m = 4q+r, j = 32w+16ss+i16) in C-regs (8 cells/lane).
// h recirculates through LDS as plain bf16, double-buffered, 1 barrier/step.
// Weights pre-scaled by -log2e (i,f,o) / -2log2e (g) so exp = bare v_exp_f32:
//   ei=2^acc_i=exp(-gi), ef=exp(-gf), eg=exp(-2gg), eo=exp(-go), ec=2^(S2*c).
//   c' = [c*(1+eg)(1+ei) + (1-eg)(1+ef)] * rcp((1+ef)(1+eg)(1+ei))
//   h  = (1-ec) * rcp((1+ec)(1+eo))
__global__ __launch_bounds__(128, 2) void lstm6(LstmP p){
  const int run = blockIdx.y;
  const int b0 = blockIdx.x * 16;
  const int t = threadIdx.x;
  const int wave = t >> 6, lane = t & 63;
  const int i16 = lane & 15, q = lane >> 4;

  // [parity][16 rows * 9 frags]; row stride 9 frags = 72 shorts (pad)
  __shared__ bfrag hb[2][16*9];
  __shared__ float xs[16*33];           // [m][s], stride 33 (pad)

  const float* __restrict__ whh = p.whh[run];

  // Whh B-fragments, pre-scaled, split hi/lo: [gate][slice][kfrag] (128 VGPR)
  bfrag Bhi[4][2][2], Blo[4][2][2];
  float wihv[4][2], bv[4][2];
#pragma unroll
  for (int g = 0; g < 4; ++g){
    const float sg = (g == 2) ? S2 : S1;
#pragma unroll
    for (int ss = 0; ss < 2; ++ss){
      const int n = 64*g + 32*wave + 16*ss + i16;     // whh row (gate index)
      const float* wr = whh + n*64;
#pragma unroll
      for (int kf = 0; kf < 2; ++kf){
        const float* src = wr + 32*kf + 8*q;
        bfrag bh, bl;
#pragma unroll
        for (int j = 0; j < 8; ++j){
          float f = src[j] * sg;
          short hi = f2bf(f);
          bh[j] = hi;
          bl[j] = f2bf(f - bf2f(hi));
        }
        Bhi[g][ss][kf] = bh; Blo[g][ss][kf] = bl;
      }
      wihv[g][ss] = p.wih[run][n] * sg;
      bv[g][ss]   = p.bias[run][n] * sg;
    }
  }
  {
    const float* x = p.x[run] + (size_t)b0 * TS;
    for (int i = t; i < 16*TS; i += 128) xs[(i>>5)*33 + (i&31)] = x[i];
    int* hz = (int*)&hb[0][0];            // zero parity-0 plane
    for (int i = t; i < 576; i += 128) hz[i] = 0;
  }
  __syncthreads();

  float c[8] = {0,0,0,0,0,0,0,0};
  float hlast[8];

  for (int s = 0; s < TS; ++s){
    const bfrag* hh = hb[s & 1];
    const int af = i16*9 + q;                    // A: m=lane&15, k=8q+j
    bfrag ah0 = hh[af];
    bfrag ah1 = hh[af + 4];
    float xm[4];
#pragma unroll
    for (int r = 0; r < 4; ++r) xm[r] = xs[(4*q + r)*33 + s];

    f32x4 acc[4][2];
#pragma unroll
    for (int g = 0; g < 4; ++g){
#pragma unroll
      for (int ss = 0; ss < 2; ++ss){
#pragma unroll
        for (int r = 0; r < 4; ++r) acc[g][ss][r] = fmaf(xm[r], wihv[g][ss], bv[g][ss]);
        acc[g][ss] = __builtin_amdgcn_mfma_f32_16x16x32_bf16(ah0, Bhi[g][ss][0], acc[g][ss], 0,0,0);
        acc[g][ss] = __builtin_amdgcn_mfma_f32_16x16x32_bf16(ah1, Bhi[g][ss][1], acc[g][ss], 0,0,0);
        acc[g][ss] = __builtin_amdgcn_mfma_f32_16x16x32_bf16(ah0, Blo[g][ss][0], acc[g][ss], 0,0,0);
        acc[g][ss] = __builtin_amdgcn_mfma_f32_16x16x32_bf16(ah1, Blo[g][ss][1], acc[g][ss], 0,0,0);
      }
    }

    short* wh = (short*)hb[(s+1) & 1];
#pragma unroll
    for (int ss = 0; ss < 2; ++ss){
#pragma unroll
      for (int r = 0; r < 4; ++r){
        float ei = __builtin_amdgcn_exp2f(acc[0][ss][r]);
        float ef = __builtin_amdgcn_exp2f(acc[1][ss][r]);
        float eg = __builtin_amdgcn_exp2f(acc[2][ss][r]);
        float eo = __builtin_amdgcn_exp2f(acc[3][ss][r]);
        float pf = 1.0f + ef;
        float D1 = (1.0f + eg) * (1.0f + ei);
        float num = fmaf(c[ss*4+r], D1, (1.0f - eg) * pf);
        float cc = num * __builtin_amdgcn_rcpf(pf * D1);
        c[ss*4+r] = cc;
        float ec = __builtin_amdgcn_exp2f(cc * S2);
        float hv = (1.0f - ec) * __builtin_amdgcn_rcpf((1.0f + ec) * (1.0f + eo));
        hlast[ss*4+r] = hv;
        wh[(4*q + r)*72 + 32*wave + 16*ss + i16] = f2bf(hv);
      }
    }
    __syncthreads();
  }

#pragma unroll
  for (int ss = 0; ss < 2; ++ss)
#pragma unroll
    for (int r = 0; r < 4; ++r){
      int m = 4*q + r, j = 32*wave + 16*ss + i16;
      p.hout[((size_t)run*BTOT + b0 + m)*64 + j] = hlast[ss*4+r];
    }
}

// Epilogue: 16 batch / block, grid (256, 2). Layer1 (256->64) split-bf16 MFMA,
// layer2 (64->6) fp32 VALU, log_softmax for i-branch. (R5 version, ~free.)
__global__ __launch_bounds__(256) void epilogue(EpiP p){
  const int br = blockIdx.y;
  const int b0 = blockIdx.x * 16;
  const int t = threadIdx.x;
  const int wave = t >> 6, lane = t & 63;
  const int i16 = lane & 15, q = lane >> 4;

  __shared__ bfrag hqv_hi[16*33], hqv_lo[16*33];   // [m][k], stride 33 frags
  __shared__ float qv[16*66];                       // layer1 out, stride 66
  __shared__ float iv[16][6];

  const float* hbase = p.hout + (size_t)br*3*BTOT*64;
  {
    short4* dh = (short4*)hqv_hi;
    short4* dl = (short4*)hqv_lo;
    for (int i = t; i < 768; i += 256){
      int run = i >> 8, ii = i & 255;
      int e = ii >> 4, j4 = ii & 15;
      float4 v = *(const float4*)(hbase + ((size_t)run*BTOT + b0 + e)*64 + j4*4);
      short4 h, l;
      short x0 = f2bf(v.x); h.x = x0; l.x = f2bf(v.x - bf2f(x0));
      short x1 = f2bf(v.y); h.y = x1; l.y = f2bf(v.y - bf2f(x1));
      short x2 = f2bf(v.z); h.z = x2; l.z = f2bf(v.z - bf2f(x2));
      short x3 = f2bf(v.w); h.w = x3; l.w = f2bf(v.w - bf2f(x3));
      int o4 = e*66 + run*16 + j4;               // short4 units
      dh[o4] = h;
      dl[o4] = l;
    }
  }
  {
    short* sh = (short*)hqv_hi;
    short* sl = (short*)hqv_lo;
    const float* w03 = p.w03[br];
    const float* b03 = p.b03[br];
    for (int i = t; i < 1024; i += 256){
      int e = i >> 6, jj = i & 63;
      const float* s2r = p.s2 + (size_t)(b0 + e)*3;
      float v = fmaf(s2r[0], w03[jj*3+0],
                fmaf(s2r[1], w03[jj*3+1],
                fmaf(s2r[2], w03[jj*3+2], b03[jj])));
      v = fmaxf(v, 0.0f);
      int off = e*264 + 192 + jj;
      short hi = f2bf(v);
      sh[off] = hi;
      sl[off] = f2bf(v - bf2f(hi));
    }
  }
  __syncthreads();

  // layer1: wave owns n-tile = wave -> output col n = 16*wave + i16
  {
    const int n = 16*wave + i16;
    const float* w1r = p.w1[br] + (size_t)n*256;
    f32x4 acc;
    { float bb = p.b1[br][n]; acc[0]=bb; acc[1]=bb; acc[2]=bb; acc[3]=bb; }
#pragma unroll
    for (int ks = 0; ks < 8; ++ks){
      bfrag ah = hqv_hi[i16*33 + 4*ks + q];
      bfrag al = hqv_lo[i16*33 + 4*ks + q];
      const float* src = w1r + 32*ks + 8*q;
      bfrag bh, bl;
#pragma unroll
      for (int j = 0; j < 8; ++j){
        float f = src[j];
        short hi = f2bf(f);
        bh[j] = hi;
        bl[j] = f2bf(f - bf2f(hi));
      }
      acc = __builtin_amdgcn_mfma_f32_16x16x32_bf16(ah, bh, acc, 0,0,0);
      acc = __builtin_amdgcn_mfma_f32_16x16x32_bf16(al, bh, acc, 0,0,0);
      acc = __builtin_amdgcn_mfma_f32_16x16x32_bf16(ah, bl, acc, 0,0,0);
    }
#pragma unroll
    for (int r = 0; r < 4; ++r)
      qv[(4*q + r)*66 + n] = fmaxf(acc[r], 0.0f);
  }
  __syncthreads();

  if (t < 96){
    int e = t / 6, a = t % 6;
    const float* w2r = p.w2[br] + a*64;
    const float* qe = qv + e*66;
    float acc2 = p.b2[br][a];
#pragma unroll 8
    for (int k = 0; k < 64; ++k) acc2 = fmaf(qe[k], w2r[k], acc2);
    int b = b0 + e;
    if (br == 0){
      p.out[(size_t)b*6 + a] = acc2;                       // q head
    } else {
      float v = fmaxf(acc2, 0.0f);
      iv[e][a] = v;
      p.out[(size_t)2*BTOT*6 + (size_t)b*6 + a] = v;       // i (third output)
    }
  }
  __syncthreads();
  if (br == 1 && t < 16){
    float m = iv[t][0];
    for (int a2 = 1; a2 < 6; ++a2) m = fmaxf(m, iv[t][a2]);
    float ss = 0.0f;
    for (int a2 = 0; a2 < 6; ++a2) ss += __expf(iv[t][a2] - m);
    float ls = __logf(ss);
    int b = b0 + t;
    for (int a2 = 0; a2 < 6; ++a2)
      p.out[(size_t)BTOT*6 + (size_t)b*6 + a2] = iv[t][a2] - m - ls;
  }
}

extern "C" void kernel_launch(void* const* d_in, const int* in_sizes, int n_in,
                              void* d_out, int out_size, void* d_ws, size_t ws_size,
                              hipStream_t stream) {
  const float* x0 = (const float*)d_in[0];
  const float* x1 = (const float*)d_in[1];
  const float* x2 = (const float*)d_in[2];
  const float* s2 = (const float*)d_in[3];

  LstmP lp;
  lp.x[0]=x0; lp.x[1]=x1; lp.x[2]=x2; lp.x[3]=x0; lp.x[4]=x1; lp.x[5]=x2;
  const int wbase[6] = {4, 7, 7, 10, 13, 16};   // q00, q01, q01, i00, i01, i02
  for (int r = 0; r < 6; ++r){
    lp.wih[r]  = (const float*)d_in[wbase[r]+0];
    lp.whh[r]  = (const float*)d_in[wbase[r]+1];
    lp.bias[r] = (const float*)d_in[wbase[r]+2];
  }
  lp.hout = (float*)d_ws;   // 6*4096*64 fp32 = 6.29 MB

  lstm6<<<dim3(BTOT/16, 6), 128, 0, stream>>>(lp);

  EpiP ep;
  ep.hout = (const float*)d_ws;
  ep.s2 = s2;
  ep.w03[0]=(const float*)d_in[19]; ep.b03[0]=(const float*)d_in[20];
  ep.w1 [0]=(const float*)d_in[21]; ep.b1 [0]=(const float*)d_in[22];
  ep.w2 [0]=(const float*)d_in[23]; ep.b2 [0]=(const float*)d_in[24];
  ep.w03[1]=(const float*)d_in[25]; ep.b03[1]=(const float*)d_in[26];
  ep.w1 [1]=(const float*)d_in[27]; ep.b1 [1]=(const float*)d_in[28];
  ep.w2 [1]=(const float*)d_in[29]; ep.b2 [1]=(const float*)d_in[30];
  ep.out = (float*)d_out;

  epilogue<<<dim3(BTOT/16, 2), 256, 0, stream>>>(ep);
}

// Round 7
// 209.605 us; speedup vs baseline: 1.2377x; 1.2377x over previous
//
#include <hip/hip_runtime.h>

#define BTOT 4096
#define TS 32

typedef __attribute__((ext_vector_type(8))) short bfrag;   // 8 bf16, 16 B
typedef __attribute__((ext_vector_type(4))) float f32x4;

#define S1 (-1.44269504089f)   // -log2(e)
#define S2 (-2.88539008178f)   // -2*log2(e)

__device__ __forceinline__ short f2bf(float f){
  union { float f; unsigned u; } v; v.f = f;
  unsigned r = v.u + 0x7FFFu + ((v.u >> 16) & 1u);   // RNE
  return (short)(r >> 16);
}
__device__ __forceinline__ float bf2f(short s){
  union { unsigned u; float f; } v; v.u = ((unsigned)(unsigned short)s) << 16; return v.f;
}

struct LstmP {
  const float* x[6];
  const float* wih[6];
  const float* whh[6];
  const float* bias[6];
  float* hout;        // [6][BTOT][64] fp32
};

struct EpiP {
  const float* hout;
  const float* s2;
  const float* w03[2]; const float* b03[2];
  const float* w1[2];  const float* b1[2];
  const float* w2[2];  const float* b2[2];
  float* out;
};

// Block: run = blockIdx.y, 16 batch rows, 2 waves.
// Wave w owns ALL 4 gates for cols j = 16*(2w+ss)+i16, ss in {0,1}:
// 16 plain-bf16 B-frags (64 VGPR), 8 cells/lane, 16 MFMA/step/wave.
// h recirculates through LDS as plain bf16, double-buffered, 1 barrier/step.
// Weights pre-scaled by -log2e (i,f,o) / -2log2e (g): exp = bare v_exp_f32.
//   c' = [c*(1+eg)(1+ei) + (1-eg)(1+ef)] * rcp((1+ef)(1+eg)(1+ei))
//   h  = (1-ec) * rcp((1+ec)(1+eo)),  ec = exp2(S2*c')
// Bounds: |preact|<=~9 -> e-terms <= e^18; products < 4e35: finite.
__global__ __launch_bounds__(128) void lstm6(LstmP p){
  const int run = blockIdx.y;
  const int b0 = blockIdx.x * 16;
  const int t = threadIdx.x;
  const int w = t >> 6, lane = t & 63;
  const int i16 = lane & 15, q = lane >> 4;

  __shared__ bfrag hb[2][16*9];   // [parity][row*9frags]; row stride 72 shorts
  __shared__ float xs[16*33];     // [m][s], stride 33 (pad)

  const float* __restrict__ whh = p.whh[run];

  // B-fragments (plain bf16, pre-scaled): [gate][ss][kfrag] = 16 frags (64 VGPR)
  bfrag B[4][2][2];
  float wihv[4][2], bv[4][2];
#pragma unroll
  for (int g = 0; g < 4; ++g){
    const float sg = (g == 2) ? S2 : S1;
#pragma unroll
    for (int ss = 0; ss < 2; ++ss){
      const int n = 64*g + 16*(2*w + ss) + i16;     // gate row index
      const float* wr = whh + n*64;
#pragma unroll
      for (int kf = 0; kf < 2; ++kf){
        const float* src = wr + 32*kf + 8*q;
        bfrag bb;
#pragma unroll
        for (int j = 0; j < 8; ++j) bb[j] = f2bf(src[j] * sg);
        B[g][ss][kf] = bb;
      }
      wihv[g][ss] = p.wih[run][n] * sg;
      bv[g][ss]   = p.bias[run][n] * sg;
    }
  }
  {
    const float* x = p.x[run] + (size_t)b0 * TS;
    for (int i = t; i < 16*TS; i += 128) xs[(i>>5)*33 + (i&31)] = x[i];
    int* hz = (int*)&hb[0][0];            // zero parity-0 plane (576 dwords)
    for (int i = t; i < 576; i += 128) hz[i] = 0;
  }
  __syncthreads();

  float c[2][4] = {{0,0,0,0},{0,0,0,0}};
  float hlast[2][4];

  for (int s = 0; s < TS; ++s){
    const bfrag* hh = hb[s & 1];
    short* wh = (short*)hb[(s+1) & 1];
    const int af = i16*9 + q;
    bfrag ah0 = hh[af];          // A: m=i16, k=8q+j      (k 0..31)
    bfrag ah1 = hh[af + 4];      //                        (k 32..63)
    float xm[4];
#pragma unroll
    for (int r = 0; r < 4; ++r) xm[r] = xs[(4*q + r)*33 + s];

#pragma unroll
    for (int ss = 0; ss < 2; ++ss){
      f32x4 acc[4];
#pragma unroll
      for (int g = 0; g < 4; ++g){
#pragma unroll
        for (int r = 0; r < 4; ++r) acc[g][r] = fmaf(xm[r], wihv[g][ss], bv[g][ss]);
        acc[g] = __builtin_amdgcn_mfma_f32_16x16x32_bf16(ah0, B[g][ss][0], acc[g], 0,0,0);
        acc[g] = __builtin_amdgcn_mfma_f32_16x16x32_bf16(ah1, B[g][ss][1], acc[g], 0,0,0);
      }
#pragma unroll
      for (int r = 0; r < 4; ++r){
        float ei = __builtin_amdgcn_exp2f(acc[0][r]);
        float ef = __builtin_amdgcn_exp2f(acc[1][r]);
        float eg = __builtin_amdgcn_exp2f(acc[2][r]);
        float eo = __builtin_amdgcn_exp2f(acc[3][r]);
        float pf = 1.0f + ef;
        float D1 = (1.0f + eg) * (1.0f + ei);
        float num = fmaf(c[ss][r], D1, (1.0f - eg) * pf);
        float cc = num * __builtin_amdgcn_rcpf(pf * D1);
        c[ss][r] = cc;
        float ec = __builtin_amdgcn_exp2f(cc * S2);
        float hv = (1.0f - ec) * __builtin_amdgcn_rcpf((1.0f + ec) * (1.0f + eo));
        hlast[ss][r] = hv;
        wh[(4*q + r)*72 + 16*(2*w + ss) + i16] = f2bf(hv);
      }
    }
    __syncthreads();
  }

#pragma unroll
  for (int ss = 0; ss < 2; ++ss)
#pragma unroll
    for (int r = 0; r < 4; ++r){
      int m = 4*q + r, j = 16*(2*w + ss) + i16;
      p.hout[((size_t)run*BTOT + b0 + m)*64 + j] = hlast[ss][r];
    }
}

// Epilogue: 16 batch / block, grid (256, 2). Layer1 (256->64) split-bf16 MFMA,
// layer2 (64->6) fp32 VALU, log_softmax for i-branch. (R5 version, ~free.)
__global__ __launch_bounds__(256) void epilogue(EpiP p){
  const int br = blockIdx.y;
  const int b0 = blockIdx.x * 16;
  const int t = threadIdx.x;
  const int wave = t >> 6, lane = t & 63;
  const int i16 = lane & 15, q = lane >> 4;

  __shared__ bfrag hqv_hi[16*33], hqv_lo[16*33];   // [m][k], stride 33 frags
  __shared__ float qv[16*66];                       // layer1 out, stride 66
  __shared__ float iv[16][6];

  const float* hbase = p.hout + (size_t)br*3*BTOT*64;
  {
    short4* dh = (short4*)hqv_hi;
    short4* dl = (short4*)hqv_lo;
    for (int i = t; i < 768; i += 256){
      int run = i >> 8, ii = i & 255;
      int e = ii >> 4, j4 = ii & 15;
      float4 v = *(const float4*)(hbase + ((size_t)run*BTOT + b0 + e)*64 + j4*4);
      short4 h, l;
      short x0 = f2bf(v.x); h.x = x0; l.x = f2bf(v.x - bf2f(x0));
      short x1 = f2bf(v.y); h.y = x1; l.y = f2bf(v.y - bf2f(x1));
      short x2 = f2bf(v.z); h.z = x2; l.z = f2bf(v.z - bf2f(x2));
      short x3 = f2bf(v.w); h.w = x3; l.w = f2bf(v.w - bf2f(x3));
      int o4 = e*66 + run*16 + j4;               // short4 units
      dh[o4] = h;
      dl[o4] = l;
    }
  }
  {
    short* sh = (short*)hqv_hi;
    short* sl = (short*)hqv_lo;
    const float* w03 = p.w03[br];
    const float* b03 = p.b03[br];
    for (int i = t; i < 1024; i += 256){
      int e = i >> 6, jj = i & 63;
      const float* s2r = p.s2 + (size_t)(b0 + e)*3;
      float v = fmaf(s2r[0], w03[jj*3+0],
                fmaf(s2r[1], w03[jj*3+1],
                fmaf(s2r[2], w03[jj*3+2], b03[jj])));
      v = fmaxf(v, 0.0f);
      int off = e*264 + 192 + jj;
      short hi = f2bf(v);
      sh[off] = hi;
      sl[off] = f2bf(v - bf2f(hi));
    }
  }
  __syncthreads();

  // layer1: wave owns n-tile = wave -> output col n = 16*wave + i16
  {
    const int n = 16*wave + i16;
    const float* w1r = p.w1[br] + (size_t)n*256;
    f32x4 acc;
    { float bb = p.b1[br][n]; acc[0]=bb; acc[1]=bb; acc[2]=bb; acc[3]=bb; }
#pragma unroll
    for (int ks = 0; ks < 8; ++ks){
      bfrag ah = hqv_hi[i16*33 + 4*ks + q];
      bfrag al = hqv_lo[i16*33 + 4*ks + q];
      const float* src = w1r + 32*ks + 8*q;
      bfrag bh, bl;
#pragma unroll
      for (int j = 0; j < 8; ++j){
        float f = src[j];
        short hi = f2bf(f);
        bh[j] = hi;
        bl[j] = f2bf(f - bf2f(hi));
      }
      acc = __builtin_amdgcn_mfma_f32_16x16x32_bf16(ah, bh, acc, 0,0,0);
      acc = __builtin_amdgcn_mfma_f32_16x16x32_bf16(al, bh, acc, 0,0,0);
      acc = __builtin_amdgcn_mfma_f32_16x16x32_bf16(ah, bl, acc, 0,0,0);
    }
#pragma unroll
    for (int r = 0; r < 4; ++r)
      qv[(4*q + r)*66 + n] = fmaxf(acc[r], 0.0f);
  }
  __syncthreads();

  if (t < 96){
    int e = t / 6, a = t % 6;
    const float* w2r = p.w2[br] + a*64;
    const float* qe = qv + e*66;
    float acc2 = p.b2[br][a];
#pragma unroll 8
    for (int k = 0; k < 64; ++k) acc2 = fmaf(qe[k], w2r[k], acc2);
    int b = b0 + e;
    if (br == 0){
      p.out[(size_t)b*6 + a] = acc2;                       // q head
    } else {
      float v = fmaxf(acc2, 0.0f);
      iv[e][a] = v;
      p.out[(size_t)2*BTOT*6 + (size_t)b*6 + a] = v;       // i (third output)
    }
  }
  __syncthreads();
  if (br == 1 && t < 16){
    float m = iv[t][0];
    for (int a2 = 1; a2 < 6; ++a2) m = fmaxf(m, iv[t][a2]);
    float ss = 0.0f;
    for (int a2 = 0; a2 < 6; ++a2) ss += __expf(iv[t][a2] - m);
    float ls = __logf(ss);
    int b = b0 + t;
    for (int a2 = 0; a2 < 6; ++a2)
      p.out[(size_t)BTOT*6 + (size_t)b*6 + a2] = iv[t][a2] - m - ls;
  }
}

extern "C" void kernel_launch(void* const* d_in, const int* in_sizes, int n_in,
                              void* d_out, int out_size, void* d_ws, size_t ws_size,
                              hipStream_t stream) {
  const float* x0 = (const float*)d_in[0];
  const float* x1 = (const float*)d_in[1];
  const float* x2 = (const float*)d_in[2];
  const float* s2 = (const float*)d_in[3];

  LstmP lp;
  lp.x[0]=x0; lp.x[1]=x1; lp.x[2]=x2; lp.x[3]=x0; lp.x[4]=x1; lp.x[5]=x2;
  const int wbase[6] = {4, 7, 7, 10, 13, 16};   // q00, q01, q01, i00, i01, i02
  for (int r = 0; r < 6; ++r){
    lp.wih[r]  = (const float*)d_in[wbase[r]+0];
    lp.whh[r]  = (const float*)d_in[wbase[r]+1];
    lp.bias[r] = (const float*)d_in[wbase[r]+2];
  }
  lp.hout = (float*)d_ws;   // 6*4096*64 fp32 = 6.29 MB

  lstm6<<<dim3(BTOT/16, 6), 128, 0, stream>>>(lp);

  EpiP ep;
  ep.hout = (const float*)d_ws;
  ep.s2 = s2;
  ep.w03[0]=(const float*)d_in[19]; ep.b03[0]=(const float*)d_in[20];
  ep.w1 [0]=(const float*)d_in[21]; ep.b1 [0]=(const float*)d_in[22];
  ep.w2 [0]=(const float*)d_in[23]; ep.b2 [0]=(const float*)d_in[24];
  ep.w03[1]=(const float*)d_in[25]; ep.b03[1]=(const float*)d_in[26];
  ep.w1 [1]=(const float*)d_in[27]; ep.b1 [1]=(const float*)d_in[28];
  ep.w2 [1]=(const float*)d_in[29]; ep.b2 [1]=(const float*)d_in[30];
  ep.out = (float*)d_out;

  epilogue<<<dim3(BTOT/16, 2), 256, 0, stream>>>(ep);
}

// Round 8
// 182.936 us; speedup vs baseline: 1.4182x; 1.1458x over previous
//
#include <hip/hip_runtime.h>

#define BTOT 4096
#define TS 32

typedef __attribute__((ext_vector_type(8))) short bfrag;   // 8 bf16, 16 B
typedef __attribute__((ext_vector_type(4))) float f32x4;

#define S1 (-1.44269504089f)   // -log2(e)
#define S2 (-2.88539008178f)   // -2*log2(e)

__device__ __forceinline__ short f2bf(float f){
  union { float f; unsigned u; } v; v.f = f;
  unsigned r = v.u + 0x7FFFu + ((v.u >> 16) & 1u);   // RNE
  return (short)(r >> 16);
}
__device__ __forceinline__ float bf2f(short s){
  union { unsigned u; float f; } v; v.u = ((unsigned)(unsigned short)s) << 16; return v.f;
}

struct LstmP {
  const float* x[6];
  const float* wih[6];
  const float* whh[6];
  const float* bias[6];
  float* hout;        // [6][BTOT][64] fp32
};

struct EpiP {
  const float* hout;
  const float* s2;
  const float* w03[2]; const float* b03[2];
  const float* w1[2];  const float* b1[2];
  const float* w2[2];  const float* b2[2];
  float* out;
};

// Block: run = blockIdx.y, 16 batch rows, 4 waves (256 thr).
// Wave w owns ALL 4 gates for cols j = 16w + i16 only: 8 plain-bf16 B-frags
// (32 VGPR), 4 cells/lane, 8 MFMA/step/wave. ~100 VGPR -> 4-5 waves/SIMD.
// h recirculates through LDS as plain bf16, double-buffered, 1 barrier/step.
// Weights pre-scaled by -log2e (i,f,o) / -2log2e (g): exp = bare v_exp_f32.
//   c' = [c*(1+eg)(1+ei) + (1-eg)(1+ef)] * rcp((1+ef)(1+eg)(1+ei))
//   h  = (1-ec) * rcp((1+ec)(1+eo)),  ec = exp2(S2*c')
__global__ __launch_bounds__(256, 4) void lstm6(LstmP p){
  const int run = blockIdx.y;
  const int b0 = blockIdx.x * 16;
  const int t = threadIdx.x;
  const int w = t >> 6, lane = t & 63;
  const int i16 = lane & 15, q = lane >> 4;

  __shared__ bfrag hb[2][16*9];   // [parity][row*9frags]; row stride 72 shorts
  __shared__ float xs[16*33];     // [m][s], stride 33 (pad)

  const float* __restrict__ whh = p.whh[run];

  // B-fragments (plain bf16, pre-scaled): [gate][kfrag] = 8 frags (32 VGPR)
  bfrag B[4][2];
  float wihv[4], bv[4];
#pragma unroll
  for (int g = 0; g < 4; ++g){
    const float sg = (g == 2) ? S2 : S1;
    const int n = 64*g + 16*w + i16;             // gate row index
    const float* wr = whh + n*64;
#pragma unroll
    for (int kf = 0; kf < 2; ++kf){
      const float* src = wr + 32*kf + 8*q;
      bfrag bb;
#pragma unroll
      for (int j = 0; j < 8; ++j) bb[j] = f2bf(src[j] * sg);
      B[g][kf] = bb;
    }
    wihv[g] = p.wih[run][n] * sg;
    bv[g]   = p.bias[run][n] * sg;
  }
  {
    const float* x = p.x[run] + (size_t)b0 * TS;
    for (int i = t; i < 16*TS; i += 256) xs[(i>>5)*33 + (i&31)] = x[i];
    int* hz = (int*)&hb[0][0];            // zero parity-0 plane (576 dwords)
    for (int i = t; i < 576; i += 256) hz[i] = 0;
  }
  __syncthreads();

  float c[4] = {0,0,0,0};
  float hlast[4];

  for (int s = 0; s < TS; ++s){
    const bfrag* hh = hb[s & 1];
    short* wh = (short*)hb[(s+1) & 1];
    const int af = i16*9 + q;
    bfrag ah0 = hh[af];          // A: m=i16, k=8q+j  (k 0..31)
    bfrag ah1 = hh[af + 4];      //                   (k 32..63)
    float xm[4];
#pragma unroll
    for (int r = 0; r < 4; ++r) xm[r] = xs[(4*q + r)*33 + s];

    f32x4 acc[4];
#pragma unroll
    for (int g = 0; g < 4; ++g){
#pragma unroll
      for (int r = 0; r < 4; ++r) acc[g][r] = fmaf(xm[r], wihv[g], bv[g]);
      acc[g] = __builtin_amdgcn_mfma_f32_16x16x32_bf16(ah0, B[g][0], acc[g], 0,0,0);
      acc[g] = __builtin_amdgcn_mfma_f32_16x16x32_bf16(ah1, B[g][1], acc[g], 0,0,0);
    }
#pragma unroll
    for (int r = 0; r < 4; ++r){
      float ei = __builtin_amdgcn_exp2f(acc[0][r]);
      float ef = __builtin_amdgcn_exp2f(acc[1][r]);
      float eg = __builtin_amdgcn_exp2f(acc[2][r]);
      float eo = __builtin_amdgcn_exp2f(acc[3][r]);
      float pf = 1.0f + ef;
      float D1 = (1.0f + eg) * (1.0f + ei);
      float num = fmaf(c[r], D1, (1.0f - eg) * pf);
      float cc = num * __builtin_amdgcn_rcpf(pf * D1);
      c[r] = cc;
      float ec = __builtin_amdgcn_exp2f(cc * S2);
      float hv = (1.0f - ec) * __builtin_amdgcn_rcpf((1.0f + ec) * (1.0f + eo));
      hlast[r] = hv;
      wh[(4*q + r)*72 + 16*w + i16] = f2bf(hv);
    }
    __syncthreads();
  }

#pragma unroll
  for (int r = 0; r < 4; ++r){
    int m = 4*q + r, j = 16*w + i16;
    p.hout[((size_t)run*BTOT + b0 + m)*64 + j] = hlast[r];
  }
}

// Epilogue: 16 batch / block, grid (256, 2). Layer1 (256->64) split-bf16 MFMA,
// layer2 (64->6) fp32 VALU, log_softmax for i-branch. (R5 version, ~free.)
__global__ __launch_bounds__(256) void epilogue(EpiP p){
  const int br = blockIdx.y;
  const int b0 = blockIdx.x * 16;
  const int t = threadIdx.x;
  const int wave = t >> 6, lane = t & 63;
  const int i16 = lane & 15, q = lane >> 4;

  __shared__ bfrag hqv_hi[16*33], hqv_lo[16*33];   // [m][k], stride 33 frags
  __shared__ float qv[16*66];                       // layer1 out, stride 66
  __shared__ float iv[16][6];

  const float* hbase = p.hout + (size_t)br*3*BTOT*64;
  {
    short4* dh = (short4*)hqv_hi;
    short4* dl = (short4*)hqv_lo;
    for (int i = t; i < 768; i += 256){
      int run = i >> 8, ii = i & 255;
      int e = ii >> 4, j4 = ii & 15;
      float4 v = *(const float4*)(hbase + ((size_t)run*BTOT + b0 + e)*64 + j4*4);
      short4 h, l;
      short x0 = f2bf(v.x); h.x = x0; l.x = f2bf(v.x - bf2f(x0));
      short x1 = f2bf(v.y); h.y = x1; l.y = f2bf(v.y - bf2f(x1));
      short x2 = f2bf(v.z); h.z = x2; l.z = f2bf(v.z - bf2f(x2));
      short x3 = f2bf(v.w); h.w = x3; l.w = f2bf(v.w - bf2f(x3));
      int o4 = e*66 + run*16 + j4;               // short4 units
      dh[o4] = h;
      dl[o4] = l;
    }
  }
  {
    short* sh = (short*)hqv_hi;
    short* sl = (short*)hqv_lo;
    const float* w03 = p.w03[br];
    const float* b03 = p.b03[br];
    for (int i = t; i < 1024; i += 256){
      int e = i >> 6, jj = i & 63;
      const float* s2r = p.s2 + (size_t)(b0 + e)*3;
      float v = fmaf(s2r[0], w03[jj*3+0],
                fmaf(s2r[1], w03[jj*3+1],
                fmaf(s2r[2], w03[jj*3+2], b03[jj])));
      v = fmaxf(v, 0.0f);
      int off = e*264 + 192 + jj;
      short hi = f2bf(v);
      sh[off] = hi;
      sl[off] = f2bf(v - bf2f(hi));
    }
  }
  __syncthreads();

  // layer1: wave owns n-tile = wave -> output col n = 16*wave + i16
  {
    const int n = 16*wave + i16;
    const float* w1r = p.w1[br] + (size_t)n*256;
    f32x4 acc;
    { float bb = p.b1[br][n]; acc[0]=bb; acc[1]=bb; acc[2]=bb; acc[3]=bb; }
#pragma unroll
    for (int ks = 0; ks < 8; ++ks){
      bfrag ah = hqv_hi[i16*33 + 4*ks + q];
      bfrag al = hqv_lo[i16*33 + 4*ks + q];
      const float* src = w1r + 32*ks + 8*q;
      bfrag bh, bl;
#pragma unroll
      for (int j = 0; j < 8; ++j){
        float f = src[j];
        short hi = f2bf(f);
        bh[j] = hi;
        bl[j] = f2bf(f - bf2f(hi));
      }
      acc = __builtin_amdgcn_mfma_f32_16x16x32_bf16(ah, bh, acc, 0,0,0);
      acc = __builtin_amdgcn_mfma_f32_16x16x32_bf16(al, bh, acc, 0,0,0);
      acc = __builtin_amdgcn_mfma_f32_16x16x32_bf16(ah, bl, acc, 0,0,0);
    }
#pragma unroll
    for (int r = 0; r < 4; ++r)
      qv[(4*q + r)*66 + n] = fmaxf(acc[r], 0.0f);
  }
  __syncthreads();

  if (t < 96){
    int e = t / 6, a = t % 6;
    const float* w2r = p.w2[br] + a*64;
    const float* qe = qv + e*66;
    float acc2 = p.b2[br][a];
#pragma unroll 8
    for (int k = 0; k < 64; ++k) acc2 = fmaf(qe[k], w2r[k], acc2);
    int b = b0 + e;
    if (br == 0){
      p.out[(size_t)b*6 + a] = acc2;                       // q head
    } else {
      float v = fmaxf(acc2, 0.0f);
      iv[e][a] = v;
      p.out[(size_t)2*BTOT*6 + (size_t)b*6 + a] = v;       // i (third output)
    }
  }
  __syncthreads();
  if (br == 1 && t < 16){
    float m = iv[t][0];
    for (int a2 = 1; a2 < 6; ++a2) m = fmaxf(m, iv[t][a2]);
    float ss = 0.0f;
    for (int a2 = 0; a2 < 6; ++a2) ss += __expf(iv[t][a2] - m);
    float ls = __logf(ss);
    int b = b0 + t;
    for (int a2 = 0; a2 < 6; ++a2)
      p.out[(size_t)BTOT*6 + (size_t)b*6 + a2] = iv[t][a2] - m - ls;
  }
}

extern "C" void kernel_launch(void* const* d_in, const int* in_sizes, int n_in,
                              void* d_out, int out_size, void* d_ws, size_t ws_size,
                              hipStream_t stream) {
  const float* x0 = (const float*)d_in[0];
  const float* x1 = (const float*)d_in[1];
  const float* x2 = (const float*)d_in[2];
  const float* s2 = (const float*)d_in[3];

  LstmP lp;
  lp.x[0]=x0; lp.x[1]=x1; lp.x[2]=x2; lp.x[3]=x0; lp.x[4]=x1; lp.x[5]=x2;
  const int wbase[6] = {4, 7, 7, 10, 13, 16};   // q00, q01, q01, i00, i01, i02
  for (int r = 0; r < 6; ++r){
    lp.wih[r]  = (const float*)d_in[wbase[r]+0];
    lp.whh[r]  = (const float*)d_in[wbase[r]+1];
    lp.bias[r] = (const float*)d_in[wbase[r]+2];
  }
  lp.hout = (float*)d_ws;   // 6*4096*64 fp32 = 6.29 MB

  lstm6<<<dim3(BTOT/16, 6), 256, 0, stream>>>(lp);

  EpiP ep;
  ep.hout = (const float*)d_ws;
  ep.s2 = s2;
  ep.w03[0]=(const float*)d_in[19]; ep.b03[0]=(const float*)d_in[20];
  ep.w1 [0]=(const float*)d_in[21]; ep.b1 [0]=(const float*)d_in[22];
  ep.w2 [0]=(const float*)d_in[23]; ep.b2 [0]=(const float*)d_in[24];
  ep.w03[1]=(const float*)d_in[25]; ep.b03[1]=(const float*)d_in[26];
  ep.w1 [1]=(const float*)d_in[27]; ep.b1 [1]=(const float*)d_in[28];
  ep.w2 [1]=(const float*)d_in[29]; ep.b2 [1]=(const float*)d_in[30];
  ep.out = (float*)d_out;

  epilogue<<<dim3(BTOT/16, 2), 256, 0, stream>>>(ep);
}